// Round 16
// baseline (207.136 us; speedup 1.0000x reference)
//
#include <hip/hip_runtime.h>
#include <cstdint>

// ---- problem constants ----
#define B_    2
#define L_    4
#define N_    2048
#define M_    1024
#define K_    32
#define DIV_  4
#define S_    8
#define F1_   128
#define PF_   64
#define CIN_  192
#define OUT_  256
#define EPS_  1e-5f

#define BL_   (B_*L_)          // 8
#define BLM_  (BL_*M_)         // 8192
#define NPTS_ (BLM_*K_)        // 262144
#define ROWS_ (BLM_*DIV_)      // 32768

// ---- workspace layout (float offsets) ----
#define OFF_FMH  0              // 3145728 floats = 8192x768 ushort (p1 aliases head)
#define OFF_IDX  3145728        // 262144 ints
#define OFF_LOC  3407872        // 1048576 floats  local4: [NPTS][4]
#define OFF_W1F  4456448        // 96
#define OFF_B1F  4456544        // 32
#define OFF_W2F  4456576        // 2048
#define OFF_B2F  4458624        // 64
#define OFF_WCB  4458688        // 98304 floats = 256x768 ushort (bf16 B^T)
#define OFF_BCF  4556992        // 256
#define OFF_P2   4557248        // 65536  (1024 blocks x 64)
#define OFF_P3   4622784        // 196608 (512 blocks x 384)

typedef __attribute__((ext_vector_type(8))) short short8;
typedef __attribute__((ext_vector_type(4))) short short4v;
typedef __attribute__((ext_vector_type(4))) float f32x4;

__device__ __forceinline__ unsigned short f2bf(float f)
{
    unsigned u = __float_as_uint(f);
    unsigned r = (u + 0x7FFFu + ((u >> 16) & 1u)) >> 16;   // RNE
    return (unsigned short)r;
}
__device__ __forceinline__ float bf2f(unsigned short h)
{
    unsigned u = ((unsigned)h) << 16;
    return __uint_as_float(u);
}

// =====================================================================
// K1: wave-per-query KNN, 8 waves/WG sharing one pt mirror (unchanged
// from round 15 — selection output bit-identical to all passing rounds).
// =====================================================================
__global__ __launch_bounds__(512) void k_knn(const float* __restrict__ points,
                                             const float* __restrict__ queries,
                                             int*   __restrict__ idxbuf,
                                             float* __restrict__ local4,
                                             float* __restrict__ p1)
{
#pragma clang fp contract(off)
    __shared__ float4 pt[N_];                    // x,y,z,pn  (32 KB)
    __shared__ unsigned bufA[8][64];             // 2 KB
    __shared__ unsigned bufN[8][64];             // 2 KB
    __shared__ float  wred[8][8];

    const int t    = threadIdx.x;
    const int lane = t & 63;
    const int wv   = t >> 6;                     // 0..7
    const int bl   = blockIdx.x >> 7;            // 128 WGs per bl
    const int m    = ((blockIdx.x & 127) << 3) + wv;

    const float* P = points  + (size_t)bl * (N_*3);
    const float* Q = queries + (size_t)bl * (M_*3);

    for (int n = t; n < N_; n += 512) {
        float x = P[n*3], y = P[n*3+1], z = P[n*3+2];
        float pn = (x*x + y*y) + z*z;            // left-assoc, no FMA
        pt[n] = make_float4(x, y, z, pn);
    }
    __syncthreads();

    const float qx = Q[m*3], qy = Q[m*3+1], qz = Q[m*3+2];
    const float qn = (qx*qx + qy*qy) + qz*qz;
    const double qxd = (double)qx, qyd = (double)qy, qzd = (double)qz;

    auto uBkey = [&](unsigned n) -> unsigned long long {
        const float4 p4 = pt[n & 2047];
        double dx = qxd - (double)p4.x, dy = qyd - (double)p4.y, dz = qzd - (double)p4.z;
        double d2d = dx*dx + dy*dy + dz*dz;
        unsigned long long uB = (unsigned long long)__double_as_longlong(d2d);
        uB = (uB & 0x8000000000000000ULL) ? ~uB : (uB | 0x8000000000000000ULL);
        return (uB & ~2047ULL) | (unsigned long long)(n & 2047);
    };
    auto cmp_less = [&](unsigned pa, unsigned pn, unsigned ca, unsigned cn) -> bool {
        bool eq = (pa == ca);
        bool pl = eq ? (pn < cn) : (pa < ca);
        bool realtie = eq && (ca != 0xFFFFFFFFu);
        if (__ballot(realtie)) {
            unsigned long long pb = uBkey(pn);
            unsigned long long cb = uBkey(cn);
            if (realtie) pl = (pb < cb);
        }
        return pl;
    };

    unsigned Aa = 0xFFFFFFFFu;
    unsigned An = 2048u + lane;
    unsigned thrA = 0xFFFFFFFFu;
    int bufcnt = 0;

    auto flushfn = [&]() {
        unsigned sa, sn;
        if (lane < bufcnt) { sa = bufA[wv][lane]; sn = bufN[wv][lane]; }
        else               { sa = 0xFFFFFFFFu;    sn = 2048u + lane; }
        for (int k = 2; k <= 64; k <<= 1) {
            for (int j = k >> 1; j >= 1; j >>= 1) {
                unsigned pa = __shfl_xor(sa, j);
                unsigned pn = __shfl_xor(sn, j);
                bool wantMin = (((lane & k) == 0) == ((lane & j) == 0));
                bool pl = cmp_less(pa, pn, sa, sn);
                if (pl == wantMin) { sa = pa; sn = pn; }
            }
        }
        int src = (31 - lane) & 63;
        unsigned ba = __shfl(sa, src);
        unsigned bn = __shfl(sn, src);
        if (lane < 32) {
            if (cmp_less(ba, bn, Aa, An)) { Aa = ba; An = bn; }
        }
        for (int j = 16; j >= 1; j >>= 1) {
            unsigned pa = __shfl_xor(Aa, j);
            unsigned pn = __shfl_xor(An, j);
            bool wantMin = ((lane & j) == 0);
            bool pl = cmp_less(pa, pn, Aa, An);
            if (pl == wantMin) { Aa = pa; An = pn; }
        }
        bufcnt = 0;
        thrA = __shfl(Aa, 31);
    };

    float4 p4 = pt[lane];
    for (int r = 0; r < 32; ++r) {
        const int n = r*64 + lane;
        float4 p4n = p4;
        if (r < 31) p4n = pt[n + 64];
        float cross = (qx*p4.x + qy*p4.y) + qz*p4.z;   // no FMA
        float d2f = (qn + p4.w) - 2.0f*cross;
        unsigned uA = __float_as_uint(d2f);
        uA = (uA & 0x80000000u) ? ~uA : (uA | 0x80000000u);
        p4 = p4n;

        bool lt = (uA <= thrA);
        unsigned long long mask = __ballot(lt);
        int cnt = __builtin_popcountll(mask);
        if (cnt == 0) continue;
        if (bufcnt + cnt > 64) {
            flushfn();
            lt = (uA <= thrA);
            mask = __ballot(lt);
            cnt = __builtin_popcountll(mask);
            if (cnt == 0) continue;
        }
        int pos = bufcnt + __builtin_popcountll(mask & ((1ULL << lane) - 1ULL));
        if (lt) { bufA[wv][pos] = uA; bufN[wv][pos] = (unsigned)n; }
        bufcnt += cnt;
    }
    if (bufcnt > 0) flushfn();

    const long long base = ((long long)bl * M_ + m) * K_;
    float lx = 0.f, ly = 0.f, lz = 0.f;
    if (lane < 32) {
        const int n = (int)An;
        idxbuf[base + lane] = n;
        const float4 pp = pt[n];
        lx = qx - pp.x; ly = qy - pp.y; lz = qz - pp.z;
        *(float4*)(local4 + (base + lane)*4) = make_float4(lx, ly, lz, 0.f);
    }
    float s0 = lx, s1 = ly, s2 = lz, s3 = lx*lx, s4 = ly*ly, s5 = lz*lz;
#pragma unroll
    for (int off = 32; off; off >>= 1) {
        s0 += __shfl_xor(s0, off); s1 += __shfl_xor(s1, off); s2 += __shfl_xor(s2, off);
        s3 += __shfl_xor(s3, off); s4 += __shfl_xor(s4, off); s5 += __shfl_xor(s5, off);
    }
    if (lane == 0) {
        wred[wv][0]=s0; wred[wv][1]=s1; wred[wv][2]=s2;
        wred[wv][3]=s3; wred[wv][4]=s4; wred[wv][5]=s5;
    }
    __syncthreads();
    if (t < 6) {
        float s = 0.f;
#pragma unroll
        for (int w = 0; w < 8; ++w) s += wred[w][t];
        p1[(long long)blockIdx.x*8 + t] = s;
    }
}

// =====================================================================
// K2: bn1-fold (replicated per block) + bn2 stats.
// 1024 blocks x 256 rows. Every block deterministically re-derives
// s1/t1 from p1 (identical across blocks); block 0 publishes w1f/b1f
// for k_shell. Then lane-per-channel h1 accumulation over 256 rows.
// =====================================================================
__global__ __launch_bounds__(256) void k_stats2(const float* __restrict__ local4,
                                                const float* __restrict__ p1,
                                                const float* __restrict__ w1,
                                                const float* __restrict__ b1,
                                                const float* __restrict__ g1,
                                                const float* __restrict__ bb1,
                                                float* __restrict__ w1f,
                                                float* __restrict__ b1f,
                                                float* __restrict__ p2)
{
    __shared__ float red[6][33];
    __shared__ float s1v[3], t1v[3];
    __shared__ float4 pts[256];
    __shared__ float  sred[4][64];
    const int t = threadIdx.x;
    const int lane = t & 63;
    const int wv   = t >> 6;

    // replicated fold1
    {
        const int c = t >> 5, i = t & 31;
        if (c < 6) {
            float s = 0.f;
            for (int w = i; w < 1024; w += 32) s += p1[w*8 + c];
            red[c][i] = s;
        }
    }
    // stage this block's 256 rows
    pts[t] = *(const float4*)(local4 + ((size_t)blockIdx.x*256 + t) * 4);
    __syncthreads();
    if (t < 3) {
        float S = 0.f, Q = 0.f;
        for (int k = 0; k < 32; ++k) { S += red[t][k]; Q += red[t+3][k]; }
        float mean = S / (float)NPTS_;
        float var  = Q / (float)NPTS_ - mean*mean;
        float r = 1.0f / sqrtf(var + EPS_);
        float sc = r * g1[t];
        s1v[t] = sc; t1v[t] = bb1[t] - mean*sc;
    }
    __syncthreads();
    if (blockIdx.x == 0 && t < 32) {
        float acc = b1[t];
        for (int i = 0; i < 3; ++i) {
            float w = w1[t*3+i];
            w1f[t*3+i] = w * s1v[i];
            acc += w * t1v[i];
        }
        b1f[t] = acc;
    }

    const int ch = lane & 31;
    const float wa = w1[ch*3], wb = w1[ch*3+1], wc = w1[ch*3+2];
    const float w0 = wa*s1v[0], w1v = wb*s1v[1], w2v = wc*s1v[2];
    const float bv = b1[ch] + wa*t1v[0] + wb*t1v[1] + wc*t1v[2];

    float s = 0.f, q = 0.f;
    const int pbase = wv*64 + (lane >> 5);
    for (int it = 0; it < 32; ++it) {
        float4 v = pts[pbase + it*2];
        float h = fmaxf(bv + w0*v.x + w1v*v.y + w2v*v.z, 0.f);
        s += h; q += h*h;
    }
    s += __shfl_xor(s, 32); q += __shfl_xor(q, 32);
    if (lane < 32) { sred[wv][lane] = s; sred[wv][32+lane] = q; }
    __syncthreads();
    if (t < 64)
        p2[blockIdx.x*64 + t] = sred[0][t]+sred[1][t]+sred[2][t]+sred[3][t];
}

// =====================================================================
// fold2: bn2 stats -> fold into w2/b2   (p2: 1024 blocks x 64)
// =====================================================================
__global__ void k_fold2(const float* __restrict__ p2,
                        const float* __restrict__ w2, const float* __restrict__ b2,
                        const float* __restrict__ g,  const float* __restrict__ bb,
                        float* __restrict__ w2f, float* __restrict__ b2f)
{
    __shared__ float s2[32], t2[32];
    int t = threadIdx.x;   // 64
    if (t < 32) {
        float S = 0, Q = 0;
        for (int b = 0; b < 1024; ++b) { S += p2[b*64+t]; Q += p2[b*64+32+t]; }
        float mean = S / (float)NPTS_;
        float var  = Q / (float)NPTS_ - mean*mean;
        float r = 1.0f / sqrtf(var + EPS_);
        float sc = r * g[t];
        s2[t] = sc; t2[t] = bb[t] - mean*sc;
    }
    __syncthreads();
    float acc = b2[t];
    for (int i = 0; i < 32; ++i) {
        float w = w2[t*32+i];
        w2f[t*32+i] = w * s2[i];
        acc += w * t2[i];
    }
    b2f[t] = acc;
}

// =====================================================================
// K3: per-(b,l,m): h1 -> h2 + shell maxpool in registers; direct bf16
// stores to fmh. (unchanged from round 15)
// =====================================================================
__global__ __launch_bounds__(256) void k_shell(const float* __restrict__ feat_prev,
                                               const int*   __restrict__ idxbuf,
                                               const float* __restrict__ local4,
                                               const float* __restrict__ w1f,
                                               const float* __restrict__ b1f,
                                               const float* __restrict__ w2f,
                                               const float* __restrict__ b2f,
                                               unsigned short* __restrict__ fmh)
{
    __shared__ float w1s[96], b1s[32];
    __shared__ int   idxs[K_];
    __shared__ float locs[K_][4];
    __shared__ __align__(16) float h1s[K_][36];

    const int t = threadIdx.x;
    const int lane = t & 63;
    const int wv   = t >> 6;
    const int blm = blockIdx.x;
    const long long base = (long long)blm * K_;

    if (t < 96)  w1s[t] = w1f[t];
    if (t >= 96 && t < 128) b1s[t-96] = b1f[t-96];
    if (t >= 128 && t < 160) idxs[t-128] = idxbuf[base + (t-128)];
    if (t < 128) ((float*)locs)[t] = local4[base*4 + t];
    __syncthreads();

    for (int j = t; j < 1024; j += 256) {
        int k = j >> 5, o = j & 31;
        float v = b1s[o] + w1s[o*3]*locs[k][0] + w1s[o*3+1]*locs[k][1] + w1s[o*3+2]*locs[k][2];
        h1s[k][o] = fmaxf(v, 0.f);
    }
    __syncthreads();

    {
        float w2c[32];
#pragma unroll
        for (int i = 0; i < 8; ++i) {
            float4 v = *(const float4*)(w2f + lane*32 + i*4);
            w2c[i*4]=v.x; w2c[i*4+1]=v.y; w2c[i*4+2]=v.z; w2c[i*4+3]=v.w;
        }
        const float b2v = b2f[lane];
        float mx = 0.0f;
#pragma unroll
        for (int kk = 0; kk < 8; ++kk) {
            const int k = wv*8 + kk;
            const float4* hp = (const float4*)&h1s[k][0];
            float acc = b2v;
#pragma unroll
            for (int c = 0; c < 8; ++c) {
                float4 h4 = hp[c];
                acc += h4.x*w2c[c*4+0];
                acc += h4.y*w2c[c*4+1];
                acc += h4.z*w2c[c*4+2];
                acc += h4.w*w2c[c*4+3];
            }
            mx = fmaxf(mx, fmaxf(acc, 0.f));
        }
        fmh[(size_t)blm*(DIV_*CIN_) + wv*CIN_ + lane] = f2bf(mx);
    }
    {
        const float* fp0 = feat_prev + (size_t)(blm / M_) * N_ * F1_;
#pragma unroll
        for (int ph = 0; ph < 2; ++ph) {
            int d = ph*2 + (t >> 7), c = t & 127;
            float mx = -3.4e38f;
#pragma unroll
            for (int j = 0; j < 8; ++j) {
                int n = idxs[d*8+j];
                mx = fmaxf(mx, fp0[(size_t)n*F1_ + c]);
            }
            fmh[(size_t)blm*(DIV_*CIN_) + d*CIN_ + 64 + c] = f2bf(mx);
        }
    }
}

// =====================================================================
// K3s: bnc stats over fmh — 512 blocks x 64 rows x 192 ch.
// =====================================================================
__global__ void k_stats3(const unsigned short* __restrict__ fmh, float* __restrict__ p3)
{
    const int t = threadIdx.x;     // 192
    const int blk = blockIdx.x;    // 512
    float s = 0.f, q = 0.f;
    const size_t base = (size_t)blk * 64 * CIN_;
    for (int r = 0; r < 64; ++r) {
        float v = bf2f(fmh[base + (size_t)r*CIN_ + t]);
        s += v; q += v*v;
    }
    p3[blk*384 + t] = s;
    p3[blk*384 + 192 + t] = q;
}

// =====================================================================
// fold3: bnc stats -> bf16 scaled B^T conv weights + f32 effective bias
// =====================================================================
__global__ __launch_bounds__(256) void k_fold3(const float* __restrict__ p3,
                                               const float* __restrict__ conv_w,
                                               const float* __restrict__ conv_b,
                                               const float* __restrict__ g,
                                               const float* __restrict__ bb,
                                               unsigned short* __restrict__ wcfb,
                                               float* __restrict__ bcf)
{
    __shared__ float sc[CIN_], tc[CIN_];
    const int t = threadIdx.x;
    if (t < CIN_) {
        float S = 0, Q = 0;
        for (int b = 0; b < 512; ++b) { S += p3[b*384+t]; Q += p3[b*384+192+t]; }
        float mean = S / (float)ROWS_;
        float var  = Q / (float)ROWS_ - mean*mean;
        float r = 1.0f / sqrtf(var + EPS_);
        float s = r * g[t];
        sc[t] = s; tc[t] = bb[t] - mean*s;
    }
    __syncthreads();
    const int lo = blockIdx.x * 3072;          // 64 blocks x 3072 elems
    for (int j = lo + t; j < lo + 3072; j += 256) {
        int o = j / 768, k = j - o*768;
        int d = k / CIN_, c = k - d*CIN_;
        wcfb[j] = f2bf(conv_w[o*768 + c*4 + d] * sc[c]);
    }
    if (blockIdx.x == 0) {
        float acc = conv_b[t];
        for (int c = 0; c < CIN_; ++c) {
            float tcv = tc[c];
#pragma unroll
            for (int d = 0; d < 4; ++d) acc += tcv * conv_w[t*768 + c*4 + d];
        }
        bcf[t] = acc;
    }
}

// =====================================================================
// K4: block-tiled MFMA GEMM  C(8192x256) = fmh(8192x768) * wcfb^T + bcf
// BM=64 BN=64 BK=64; 512 blocks (2/CU) for stage/compute overlap.
// =====================================================================
__global__ __launch_bounds__(256) void k_gemm(const unsigned short* __restrict__ A,
                                              const unsigned short* __restrict__ Wb,
                                              const float* __restrict__ bias,
                                              float* __restrict__ C)
{
    __shared__ __align__(16) unsigned short As[64][72];
    __shared__ __align__(16) unsigned short Bs[64][72];
    const int t = threadIdx.x;
    const int lane = t & 63;
    const int wv = t >> 6;
    const int row0 = (blockIdx.x >> 2) * 64;
    const int col0 = (blockIdx.x & 3) * 64;
    const int wr = wv >> 1, wc = wv & 1;
    const int r16 = lane & 15, kq = lane >> 4;

    f32x4 acc[2][2];
#pragma unroll
    for (int i = 0; i < 2; ++i)
#pragma unroll
        for (int j = 0; j < 2; ++j) acc[i][j] = (f32x4){0.f,0.f,0.f,0.f};

    for (int kt = 0; kt < 12; ++kt) {
#pragma unroll
        for (int p = 0; p < 2; ++p) {
            int j = p*256 + t;
            int r = j >> 3, kc = (j & 7) * 8;
            *(short8*)&As[r][kc] = *(const short8*)(A + (size_t)(row0 + r)*768 + kt*64 + kc);
        }
#pragma unroll
        for (int p = 0; p < 2; ++p) {
            int j = p*256 + t;
            int r = j >> 3, kc = (j & 7) * 8;
            *(short8*)&Bs[r][kc] = *(const short8*)(Wb + (size_t)(col0 + r)*768 + kt*64 + kc);
        }
        __syncthreads();
#pragma unroll
        for (int ks = 0; ks < 2; ++ks) {
            short8 bf[2];
#pragma unroll
            for (int n = 0; n < 2; ++n) {
                const unsigned short* pb = &Bs[wc*32 + n*16 + r16][ks*32 + kq*4];
                short4v b0 = *(const short4v*)pb;
                short4v b1 = *(const short4v*)(pb + 16);
                bf[n][0]=b0[0]; bf[n][1]=b0[1]; bf[n][2]=b0[2]; bf[n][3]=b0[3];
                bf[n][4]=b1[0]; bf[n][5]=b1[1]; bf[n][6]=b1[2]; bf[n][7]=b1[3];
            }
#pragma unroll
            for (int mf = 0; mf < 2; ++mf) {
                const unsigned short* pa = &As[wr*32 + mf*16 + r16][ks*32 + kq*4];
                short4v a0 = *(const short4v*)pa;
                short4v a1 = *(const short4v*)(pa + 16);
                short8 af;
                af[0]=a0[0]; af[1]=a0[1]; af[2]=a0[2]; af[3]=a0[3];
                af[4]=a1[0]; af[5]=a1[1]; af[6]=a1[2]; af[7]=a1[3];
                acc[mf][0] = __builtin_amdgcn_mfma_f32_16x16x32_bf16(af, bf[0], acc[mf][0], 0, 0, 0);
                acc[mf][1] = __builtin_amdgcn_mfma_f32_16x16x32_bf16(af, bf[1], acc[mf][1], 0, 0, 0);
            }
        }
        __syncthreads();
    }

#pragma unroll
    for (int mf = 0; mf < 2; ++mf) {
#pragma unroll
        for (int n = 0; n < 2; ++n) {
            const int col = col0 + wc*32 + n*16 + r16;
            const float bv = bias[col];
#pragma unroll
            for (int i = 0; i < 4; ++i) {
                int row = row0 + wr*32 + mf*16 + kq*4 + i;
                C[(size_t)row*256 + col] = acc[mf][n][i] + bv;
            }
        }
    }
}

// =====================================================================
extern "C" void kernel_launch(void* const* d_in, const int* in_sizes, int n_in,
                              void* d_out, int out_size, void* d_ws, size_t ws_size,
                              hipStream_t stream)
{
    const float* points    = (const float*)d_in[0];
    const float* queries   = (const float*)d_in[1];
    const float* feat_prev = (const float*)d_in[2];
    const float* bn1g = (const float*)d_in[3];
    const float* bn1b = (const float*)d_in[4];
    const float* w1   = (const float*)d_in[5];
    const float* b1   = (const float*)d_in[6];
    const float* bn2g = (const float*)d_in[7];
    const float* bn2b = (const float*)d_in[8];
    const float* w2   = (const float*)d_in[9];
    const float* b2   = (const float*)d_in[10];
    const float* bncg = (const float*)d_in[11];
    const float* bncb = (const float*)d_in[12];
    const float* convw= (const float*)d_in[13];
    const float* convb= (const float*)d_in[14];

    float* ws   = (float*)d_ws;
    unsigned short* fmh = (unsigned short*)(ws + OFF_FMH);
    int*   idxb = (int*)(ws + OFF_IDX);
    float* loc4 = ws + OFF_LOC;
    float* w1f  = ws + OFF_W1F;
    float* b1f  = ws + OFF_B1F;
    float* w2f  = ws + OFF_W2F;
    float* b2f  = ws + OFF_B2F;
    unsigned short* wcfb = (unsigned short*)(ws + OFF_WCB);
    float* bcf  = ws + OFF_BCF;
    float* p1   = ws + OFF_FMH;    // aliases fmh head; consumed before k_shell writes fmh
    float* p2   = ws + OFF_P2;
    float* p3   = ws + OFF_P3;

    k_knn   <<<1024, 512, 0, stream>>>(points, queries, idxb, loc4, p1);
    k_stats2<<<1024, 256, 0, stream>>>(loc4, p1, w1, b1, bn1g, bn1b, w1f, b1f, p2);
    k_fold2 <<<1, 64, 0, stream>>>(p2, w2, b2, bn2g, bn2b, w2f, b2f);
    k_shell <<<BLM_, 256, 0, stream>>>(feat_prev, idxb, loc4, w1f, b1f, w2f, b2f, fmh);
    k_stats3<<<512, 192, 0, stream>>>(fmh, p3);
    k_fold3 <<<64, 256, 0, stream>>>(p3, convw, convb, bncg, bncb, wcfb, bcf);
    k_gemm  <<<512, 256, 0, stream>>>(fmh, wcfb, bcf, (float*)d_out);
}

// Round 17
// 172.091 us; speedup vs baseline: 1.2036x; 1.2036x over previous
//
#include <hip/hip_runtime.h>
#include <cstdint>

// ---- problem constants ----
#define B_    2
#define L_    4
#define N_    2048
#define M_    1024
#define K_    32
#define DIV_  4
#define S_    8
#define F1_   128
#define PF_   64
#define CIN_  192
#define OUT_  256
#define EPS_  1e-5f

#define BL_   (B_*L_)          // 8
#define BLM_  (BL_*M_)         // 8192
#define NPTS_ (BLM_*K_)        // 262144
#define ROWS_ (BLM_*DIV_)      // 32768

// ---- workspace layout (float offsets) ----
#define OFF_FMH  0              // 3145728 floats = 8192x768 ushort (p1 aliases head)
#define OFF_IDX  3145728        // 262144 ints
#define OFF_LOC  3407872        // 1048576 floats  local4: [NPTS][4]
#define OFF_W1F  4456448        // 96
#define OFF_B1F  4456544        // 32
#define OFF_W2F  4456576        // 2048
#define OFF_B2F  4458624        // 64
#define OFF_WCB  4458688        // 98304 floats = 256x768 ushort (bf16 B^T)
#define OFF_BCF  4556992        // 256
#define OFF_P2   4557248        // 16384  (256 blocks x 64)
#define OFF_P3   4573632        // 49152  (128 blocks x 384)

typedef __attribute__((ext_vector_type(8))) short short8;
typedef __attribute__((ext_vector_type(4))) short short4v;
typedef __attribute__((ext_vector_type(4))) float f32x4;

__device__ __forceinline__ unsigned short f2bf(float f)
{
    unsigned u = __float_as_uint(f);
    unsigned r = (u + 0x7FFFu + ((u >> 16) & 1u)) >> 16;   // RNE
    return (unsigned short)r;
}
__device__ __forceinline__ float bf2f(unsigned short h)
{
    unsigned u = ((unsigned)h) << 16;
    return __uint_as_float(u);
}

// =====================================================================
// K1: wave-per-query KNN, 8 waves/WG sharing one pt mirror (pair-sort
// with lazy f64 tie-break — unchanged from rounds 15/16; selection
// output bit-identical to all passing rounds).
// =====================================================================
__global__ __launch_bounds__(512) void k_knn(const float* __restrict__ points,
                                             const float* __restrict__ queries,
                                             int*   __restrict__ idxbuf,
                                             float* __restrict__ local4,
                                             float* __restrict__ p1)
{
#pragma clang fp contract(off)
    __shared__ float4 pt[N_];                    // x,y,z,pn  (32 KB)
    __shared__ unsigned bufA[8][64];             // 2 KB
    __shared__ unsigned bufN[8][64];             // 2 KB
    __shared__ float  wred[8][8];

    const int t    = threadIdx.x;
    const int lane = t & 63;
    const int wv   = t >> 6;                     // 0..7
    const int bl   = blockIdx.x >> 7;            // 128 WGs per bl
    const int m    = ((blockIdx.x & 127) << 3) + wv;

    const float* P = points  + (size_t)bl * (N_*3);
    const float* Q = queries + (size_t)bl * (M_*3);

    for (int n = t; n < N_; n += 512) {
        float x = P[n*3], y = P[n*3+1], z = P[n*3+2];
        float pn = (x*x + y*y) + z*z;            // left-assoc, no FMA
        pt[n] = make_float4(x, y, z, pn);
    }
    __syncthreads();

    const float qx = Q[m*3], qy = Q[m*3+1], qz = Q[m*3+2];
    const float qn = (qx*qx + qy*qy) + qz*qz;
    const double qxd = (double)qx, qyd = (double)qy, qzd = (double)qz;

    auto uBkey = [&](unsigned n) -> unsigned long long {
        const float4 p4 = pt[n & 2047];
        double dx = qxd - (double)p4.x, dy = qyd - (double)p4.y, dz = qzd - (double)p4.z;
        double d2d = dx*dx + dy*dy + dz*dz;
        unsigned long long uB = (unsigned long long)__double_as_longlong(d2d);
        uB = (uB & 0x8000000000000000ULL) ? ~uB : (uB | 0x8000000000000000ULL);
        return (uB & ~2047ULL) | (unsigned long long)(n & 2047);
    };
    auto cmp_less = [&](unsigned pa, unsigned pn, unsigned ca, unsigned cn) -> bool {
        bool eq = (pa == ca);
        bool pl = eq ? (pn < cn) : (pa < ca);
        bool realtie = eq && (ca != 0xFFFFFFFFu);
        if (__ballot(realtie)) {
            unsigned long long pb = uBkey(pn);
            unsigned long long cb = uBkey(cn);
            if (realtie) pl = (pb < cb);
        }
        return pl;
    };

    unsigned Aa = 0xFFFFFFFFu;
    unsigned An = 2048u + lane;
    unsigned thrA = 0xFFFFFFFFu;
    int bufcnt = 0;

    auto flushfn = [&]() {
        unsigned sa, sn;
        if (lane < bufcnt) { sa = bufA[wv][lane]; sn = bufN[wv][lane]; }
        else               { sa = 0xFFFFFFFFu;    sn = 2048u + lane; }
        for (int k = 2; k <= 64; k <<= 1) {
            for (int j = k >> 1; j >= 1; j >>= 1) {
                unsigned pa = __shfl_xor(sa, j);
                unsigned pn = __shfl_xor(sn, j);
                bool wantMin = (((lane & k) == 0) == ((lane & j) == 0));
                bool pl = cmp_less(pa, pn, sa, sn);
                if (pl == wantMin) { sa = pa; sn = pn; }
            }
        }
        int src = (31 - lane) & 63;
        unsigned ba = __shfl(sa, src);
        unsigned bn = __shfl(sn, src);
        if (lane < 32) {
            if (cmp_less(ba, bn, Aa, An)) { Aa = ba; An = bn; }
        }
        for (int j = 16; j >= 1; j >>= 1) {
            unsigned pa = __shfl_xor(Aa, j);
            unsigned pn = __shfl_xor(An, j);
            bool wantMin = ((lane & j) == 0);
            bool pl = cmp_less(pa, pn, Aa, An);
            if (pl == wantMin) { Aa = pa; An = pn; }
        }
        bufcnt = 0;
        thrA = __shfl(Aa, 31);
    };

    float4 p4 = pt[lane];
    for (int r = 0; r < 32; ++r) {
        const int n = r*64 + lane;
        float4 p4n = p4;
        if (r < 31) p4n = pt[n + 64];
        float cross = (qx*p4.x + qy*p4.y) + qz*p4.z;   // no FMA
        float d2f = (qn + p4.w) - 2.0f*cross;
        unsigned uA = __float_as_uint(d2f);
        uA = (uA & 0x80000000u) ? ~uA : (uA | 0x80000000u);
        p4 = p4n;

        bool lt = (uA <= thrA);
        unsigned long long mask = __ballot(lt);
        int cnt = __builtin_popcountll(mask);
        if (cnt == 0) continue;
        if (bufcnt + cnt > 64) {
            flushfn();
            lt = (uA <= thrA);
            mask = __ballot(lt);
            cnt = __builtin_popcountll(mask);
            if (cnt == 0) continue;
        }
        int pos = bufcnt + __builtin_popcountll(mask & ((1ULL << lane) - 1ULL));
        if (lt) { bufA[wv][pos] = uA; bufN[wv][pos] = (unsigned)n; }
        bufcnt += cnt;
    }
    if (bufcnt > 0) flushfn();

    const long long base = ((long long)bl * M_ + m) * K_;
    float lx = 0.f, ly = 0.f, lz = 0.f;
    if (lane < 32) {
        const int n = (int)An;
        idxbuf[base + lane] = n;
        const float4 pp = pt[n];
        lx = qx - pp.x; ly = qy - pp.y; lz = qz - pp.z;
        *(float4*)(local4 + (base + lane)*4) = make_float4(lx, ly, lz, 0.f);
    }
    float s0 = lx, s1 = ly, s2 = lz, s3 = lx*lx, s4 = ly*ly, s5 = lz*lz;
#pragma unroll
    for (int off = 32; off; off >>= 1) {
        s0 += __shfl_xor(s0, off); s1 += __shfl_xor(s1, off); s2 += __shfl_xor(s2, off);
        s3 += __shfl_xor(s3, off); s4 += __shfl_xor(s4, off); s5 += __shfl_xor(s5, off);
    }
    if (lane == 0) {
        wred[wv][0]=s0; wred[wv][1]=s1; wred[wv][2]=s2;
        wred[wv][3]=s3; wred[wv][4]=s4; wred[wv][5]=s5;
    }
    __syncthreads();
    if (t < 6) {
        float s = 0.f;
#pragma unroll
        for (int w = 0; w < 8; ++w) s += wred[w][t];
        p1[(long long)blockIdx.x*8 + t] = s;
    }
}

// =====================================================================
// fold1: reduce 1024 WG partials, fold bn1 into w1/b1
// =====================================================================
__global__ __launch_bounds__(256) void k_fold1(const float* __restrict__ p1,
                        const float* __restrict__ w1, const float* __restrict__ b1,
                        const float* __restrict__ g,  const float* __restrict__ bb,
                        float* __restrict__ w1f, float* __restrict__ b1f)
{
    __shared__ float red[6][33];
    __shared__ float s1[3], t1[3];
    const int t = threadIdx.x;
    const int c = t >> 5, i = t & 31;
    if (c < 6) {
        float s = 0.f;
        for (int w = i; w < 1024; w += 32) s += p1[w*8 + c];
        red[c][i] = s;
    }
    __syncthreads();
    if (t < 3) {
        float S = 0.f, Q = 0.f;
        for (int k = 0; k < 32; ++k) { S += red[t][k]; Q += red[t+3][k]; }
        float mean = S / (float)NPTS_;
        float var  = Q / (float)NPTS_ - mean*mean;
        float r = 1.0f / sqrtf(var + EPS_);
        float sc = r * g[t];
        s1[t] = sc; t1[t] = bb[t] - mean*sc;
    }
    __syncthreads();
    if (t < 32) {
        float acc = b1[t];
        for (int i2 = 0; i2 < 3; ++i2) {
            float w = w1[t*3+i2];
            w1f[t*3+i2] = w * s1[i2];
            acc += w * t1[i2];
        }
        b1f[t] = acc;
    }
}

// =====================================================================
// K2: bn2 stats — lane-per-channel accumulation, shfl reduce.
// 256 blocks x 1024 rows (round-13 structure).
// =====================================================================
__global__ __launch_bounds__(256) void k_stats2(const float* __restrict__ local4,
                                                const float* __restrict__ w1f,
                                                const float* __restrict__ b1f,
                                                float* __restrict__ p2)
{
    __shared__ float4 pts[1024];
    __shared__ float  sred[4][64];
    const int t = threadIdx.x;
    const int lane = t & 63;
    const int wv   = t >> 6;
    const int base = blockIdx.x * 1024;

    for (int j = t; j < 1024; j += 256)
        pts[j] = *(const float4*)(local4 + (size_t)(base + j) * 4);

    const int ch = lane & 31;
    const float w0 = w1f[ch*3], w1v = w1f[ch*3+1], w2v = w1f[ch*3+2];
    const float bv = b1f[ch];
    __syncthreads();

    float s = 0.f, q = 0.f;
    const int pbase = wv*256 + (lane >> 5);
    for (int it = 0; it < 128; ++it) {
        float4 v = pts[pbase + it*2];
        float h = fmaxf(bv + w0*v.x + w1v*v.y + w2v*v.z, 0.f);
        s += h; q += h*h;
    }
    s += __shfl_xor(s, 32); q += __shfl_xor(q, 32);
    if (lane < 32) { sred[wv][lane] = s; sred[wv][32+lane] = q; }
    __syncthreads();
    if (t < 64)
        p2[blockIdx.x*64 + t] = sred[0][t]+sred[1][t]+sred[2][t]+sred[3][t];
}

// =====================================================================
// fold2: bn2 stats -> fold into w2/b2  (p2: 256 blocks x 64)
// =====================================================================
__global__ void k_fold2(const float* __restrict__ p2,
                        const float* __restrict__ w2, const float* __restrict__ b2,
                        const float* __restrict__ g,  const float* __restrict__ bb,
                        float* __restrict__ w2f, float* __restrict__ b2f)
{
    __shared__ float s2[32], t2[32];
    int t = threadIdx.x;   // 64
    if (t < 32) {
        float S = 0, Q = 0;
        for (int b = 0; b < 256; ++b) { S += p2[b*64+t]; Q += p2[b*64+32+t]; }
        float mean = S / (float)NPTS_;
        float var  = Q / (float)NPTS_ - mean*mean;
        float r = 1.0f / sqrtf(var + EPS_);
        float sc = r * g[t];
        s2[t] = sc; t2[t] = bb[t] - mean*sc;
    }
    __syncthreads();
    float acc = b2[t];
    for (int i = 0; i < 32; ++i) {
        float w = w2[t*32+i];
        w2f[t*32+i] = w * s2[i];
        acc += w * t2[i];
    }
    b2f[t] = acc;
}

// =====================================================================
// K3: 4 queries per block. Weights staged in LDS ONCE (w2 column then
// held in registers), then loop over the block's 4 (b,l,m) rows:
// h1 -> h2 + shell maxpool (registers) -> feat_prev gather -> fmrow ->
// coalesced bf16 store. Numerics identical to the round-13 k_shell.
// =====================================================================
__global__ __launch_bounds__(256) void k_shell(const float* __restrict__ feat_prev,
                                               const int*   __restrict__ idxbuf,
                                               const float* __restrict__ local4,
                                               const float* __restrict__ w1f,
                                               const float* __restrict__ b1f,
                                               const float* __restrict__ w2f,
                                               const float* __restrict__ b2f,
                                               unsigned short* __restrict__ fmh)
{
    __shared__ float w1s[96], b1s[32], b2s[64];
    __shared__ float w2s[64][33];                 // w2s[o][i] = w2f[o*32+i]
    __shared__ int   idxs[K_];
    __shared__ float locs[K_][4];
    __shared__ __align__(16) float h1s[K_][36];
    __shared__ float fmrow[DIV_][CIN_];

    const int t = threadIdx.x;
    const int lane = t & 63;
    const int wv   = t >> 6;

    for (int j = t; j < 2048; j += 256) { int o = j >> 5, i = j & 31; w2s[o][i] = w2f[j]; }
    if (t < 96) w1s[t] = w1f[t];
    if (t >= 96 && t < 128) b1s[t-96] = b1f[t-96];
    if (t >= 128 && t < 192) b2s[t-128] = b2f[t-128];
    __syncthreads();

    float w2c[32];
#pragma unroll
    for (int i = 0; i < 32; ++i) w2c[i] = w2s[lane][i];   // (lane+i)%32 banks: conflict-free
    const float b2v = b2s[lane];

    for (int q = 0; q < 4; ++q) {
        const int blm = (blockIdx.x << 2) + q;
        const long long base = (long long)blm * K_;
        if (t < 32)  idxs[t] = idxbuf[base + t];
        if (t >= 64 && t < 192) ((float*)locs)[t-64] = local4[base*4 + (t-64)];
        __syncthreads();

        for (int j = t; j < 1024; j += 256) {
            int k = j >> 5, o = j & 31;
            float v = b1s[o] + w1s[o*3]*locs[k][0] + w1s[o*3+1]*locs[k][1] + w1s[o*3+2]*locs[k][2];
            h1s[k][o] = fmaxf(v, 0.f);
        }
        __syncthreads();

        // h2 + shell maxpool: wave wv = shell wv, lane = output channel
        {
            float mx = 0.0f;                       // relu outputs >= 0
#pragma unroll
            for (int kk = 0; kk < 8; ++kk) {
                const int k = wv*8 + kk;
                const float4* hp = (const float4*)&h1s[k][0];   // uniform addr -> broadcast
                float acc = b2v;
#pragma unroll
                for (int c = 0; c < 8; ++c) {
                    float4 h4 = hp[c];
                    acc += h4.x*w2c[c*4+0];
                    acc += h4.y*w2c[c*4+1];
                    acc += h4.z*w2c[c*4+2];
                    acc += h4.w*w2c[c*4+3];
                }
                mx = fmaxf(mx, fmaxf(acc, 0.f));
            }
            fmrow[wv][lane] = mx;
        }
        // feat_prev gather + shell maxpool
        {
            const float* fp0 = feat_prev + (size_t)(blm / M_) * N_ * F1_;
#pragma unroll
            for (int ph = 0; ph < 2; ++ph) {
                int d = ph*2 + (t >> 7), c = t & 127;
                float mx = -3.4e38f;
#pragma unroll
                for (int j = 0; j < 8; ++j) {
                    int n = idxs[d*8+j];
                    mx = fmaxf(mx, fp0[(size_t)n*F1_ + c]);
                }
                fmrow[d][64 + c] = mx;
            }
        }
        __syncthreads();
        for (int j = t; j < DIV_*CIN_; j += 256)
            fmh[(size_t)blm*(DIV_*CIN_) + j] = f2bf((&fmrow[0][0])[j]);
        __syncthreads();
    }
}

// =====================================================================
// K3s: bnc stats over fmh — 128 blocks x 256 rows x 192 ch.
// =====================================================================
__global__ void k_stats3(const unsigned short* __restrict__ fmh, float* __restrict__ p3)
{
    const int t = threadIdx.x;     // 192
    const int blk = blockIdx.x;    // 128
    float s = 0.f, q = 0.f;
    const size_t base = (size_t)blk * 256 * CIN_;
    for (int r = 0; r < 256; ++r) {
        float v = bf2f(fmh[base + (size_t)r*CIN_ + t]);
        s += v; q += v*v;
    }
    p3[blk*384 + t] = s;
    p3[blk*384 + 192 + t] = q;
}

// =====================================================================
// fold3: bnc stats -> bf16 scaled B^T conv weights + f32 effective bias
// =====================================================================
__global__ __launch_bounds__(256) void k_fold3(const float* __restrict__ p3,
                                               const float* __restrict__ conv_w,
                                               const float* __restrict__ conv_b,
                                               const float* __restrict__ g,
                                               const float* __restrict__ bb,
                                               unsigned short* __restrict__ wcfb,
                                               float* __restrict__ bcf)
{
    __shared__ float sc[CIN_], tc[CIN_];
    const int t = threadIdx.x;
    if (t < CIN_) {
        float S = 0, Q = 0;
        for (int b = 0; b < 128; ++b) { S += p3[b*384+t]; Q += p3[b*384+192+t]; }
        float mean = S / (float)ROWS_;
        float var  = Q / (float)ROWS_ - mean*mean;
        float r = 1.0f / sqrtf(var + EPS_);
        float s = r * g[t];
        sc[t] = s; tc[t] = bb[t] - mean*s;
    }
    __syncthreads();
    const int lo = blockIdx.x * 3072;          // 64 blocks x 3072 elems
    for (int j = lo + t; j < lo + 3072; j += 256) {
        int o = j / 768, k = j - o*768;
        int d = k / CIN_, c = k - d*CIN_;
        wcfb[j] = f2bf(conv_w[o*768 + c*4 + d] * sc[c]);
    }
    if (blockIdx.x == 0) {
        float acc = conv_b[t];
        for (int c = 0; c < CIN_; ++c) {
            float tcv = tc[c];
#pragma unroll
            for (int d = 0; d < 4; ++d) acc += tcv * conv_w[t*768 + c*4 + d];
        }
        bcf[t] = acc;
    }
}

// =====================================================================
// K4: block-tiled MFMA GEMM  C(8192x256) = fmh(8192x768) * wcfb^T + bcf
// BM=128 BN=64 BK=64; 256 blocks (round-13 configuration).
// =====================================================================
__global__ __launch_bounds__(256) void k_gemm(const unsigned short* __restrict__ A,
                                              const unsigned short* __restrict__ Wb,
                                              const float* __restrict__ bias,
                                              float* __restrict__ C)
{
    __shared__ __align__(16) unsigned short As[128][72];
    __shared__ __align__(16) unsigned short Bs[64][72];
    const int t = threadIdx.x;
    const int lane = t & 63;
    const int wv = t >> 6;
    const int row0 = (blockIdx.x >> 2) * 128;
    const int col0 = (blockIdx.x & 3) * 64;
    const int wr = wv >> 1, wc = wv & 1;
    const int r16 = lane & 15, kq = lane >> 4;

    f32x4 acc[4][2];
#pragma unroll
    for (int i = 0; i < 4; ++i)
#pragma unroll
        for (int j = 0; j < 2; ++j) acc[i][j] = (f32x4){0.f,0.f,0.f,0.f};

    for (int kt = 0; kt < 12; ++kt) {
#pragma unroll
        for (int p = 0; p < 4; ++p) {
            int j = p*256 + t;
            int r = j >> 3, kc = (j & 7) * 8;
            *(short8*)&As[r][kc] = *(const short8*)(A + (size_t)(row0 + r)*768 + kt*64 + kc);
        }
#pragma unroll
        for (int p = 0; p < 2; ++p) {
            int j = p*256 + t;
            int r = j >> 3, kc = (j & 7) * 8;
            *(short8*)&Bs[r][kc] = *(const short8*)(Wb + (size_t)(col0 + r)*768 + kt*64 + kc);
        }
        __syncthreads();
#pragma unroll
        for (int ks = 0; ks < 2; ++ks) {
            short8 bf[2];
#pragma unroll
            for (int n = 0; n < 2; ++n) {
                const unsigned short* pb = &Bs[wc*32 + n*16 + r16][ks*32 + kq*4];
                short4v b0 = *(const short4v*)pb;
                short4v b1 = *(const short4v*)(pb + 16);
                bf[n][0]=b0[0]; bf[n][1]=b0[1]; bf[n][2]=b0[2]; bf[n][3]=b0[3];
                bf[n][4]=b1[0]; bf[n][5]=b1[1]; bf[n][6]=b1[2]; bf[n][7]=b1[3];
            }
#pragma unroll
            for (int mf = 0; mf < 4; ++mf) {
                const unsigned short* pa = &As[wr*64 + mf*16 + r16][ks*32 + kq*4];
                short4v a0 = *(const short4v*)pa;
                short4v a1 = *(const short4v*)(pa + 16);
                short8 af;
                af[0]=a0[0]; af[1]=a0[1]; af[2]=a0[2]; af[3]=a0[3];
                af[4]=a1[0]; af[5]=a1[1]; af[6]=a1[2]; af[7]=a1[3];
                acc[mf][0] = __builtin_amdgcn_mfma_f32_16x16x32_bf16(af, bf[0], acc[mf][0], 0, 0, 0);
                acc[mf][1] = __builtin_amdgcn_mfma_f32_16x16x32_bf16(af, bf[1], acc[mf][1], 0, 0, 0);
            }
        }
        __syncthreads();
    }

#pragma unroll
    for (int mf = 0; mf < 4; ++mf) {
#pragma unroll
        for (int n = 0; n < 2; ++n) {
            const int col = col0 + wc*32 + n*16 + r16;
            const float bv = bias[col];
#pragma unroll
            for (int i = 0; i < 4; ++i) {
                int row = row0 + wr*64 + mf*16 + kq*4 + i;
                C[(size_t)row*256 + col] = acc[mf][n][i] + bv;
            }
        }
    }
}

// =====================================================================
extern "C" void kernel_launch(void* const* d_in, const int* in_sizes, int n_in,
                              void* d_out, int out_size, void* d_ws, size_t ws_size,
                              hipStream_t stream)
{
    const float* points    = (const float*)d_in[0];
    const float* queries   = (const float*)d_in[1];
    const float* feat_prev = (const float*)d_in[2];
    const float* bn1g = (const float*)d_in[3];
    const float* bn1b = (const float*)d_in[4];
    const float* w1   = (const float*)d_in[5];
    const float* b1   = (const float*)d_in[6];
    const float* bn2g = (const float*)d_in[7];
    const float* bn2b = (const float*)d_in[8];
    const float* w2   = (const float*)d_in[9];
    const float* b2   = (const float*)d_in[10];
    const float* bncg = (const float*)d_in[11];
    const float* bncb = (const float*)d_in[12];
    const float* convw= (const float*)d_in[13];
    const float* convb= (const float*)d_in[14];

    float* ws   = (float*)d_ws;
    unsigned short* fmh = (unsigned short*)(ws + OFF_FMH);
    int*   idxb = (int*)(ws + OFF_IDX);
    float* loc4 = ws + OFF_LOC;
    float* w1f  = ws + OFF_W1F;
    float* b1f  = ws + OFF_B1F;
    float* w2f  = ws + OFF_W2F;
    float* b2f  = ws + OFF_B2F;
    unsigned short* wcfb = (unsigned short*)(ws + OFF_WCB);
    float* bcf  = ws + OFF_BCF;
    float* p1   = ws + OFF_FMH;    // aliases fmh head; consumed before k_shell writes fmh
    float* p2   = ws + OFF_P2;
    float* p3   = ws + OFF_P3;

    k_knn   <<<1024, 512, 0, stream>>>(points, queries, idxb, loc4, p1);
    k_fold1 <<<1, 256, 0, stream>>>(p1, w1, b1, bn1g, bn1b, w1f, b1f);
    k_stats2<<<256, 256, 0, stream>>>(loc4, w1f, b1f, p2);
    k_fold2 <<<1, 64, 0, stream>>>(p2, w2, b2, bn2g, bn2b, w2f, b2f);
    k_shell <<<BLM_/4, 256, 0, stream>>>(feat_prev, idxb, loc4, w1f, b1f, w2f, b2f, fmh);
    k_stats3<<<128, 192, 0, stream>>>(fmh, p3);
    k_fold3 <<<64, 256, 0, stream>>>(p3, convw, convb, bncg, bncb, wcfb, bcf);
    k_gemm  <<<256, 256, 0, stream>>>(fmh, wcfb, bcf, (float*)d_out);
}